// Round 12
// baseline (546.671 us; speedup 1.0000x reference)
//
#include <hip/hip_runtime.h>
#include <hip/hip_bf16.h>

#define T_TOKENS 2048
#define H_DIM    2048
#define I_DIM    1408
#define E_NUM    8

typedef __bf16 bf16;
typedef __attribute__((ext_vector_type(8))) __bf16  bf16x8;
typedef __attribute__((ext_vector_type(4))) float   floatx4;

// ---------------- ws layout (bytes) ----------------
// No packed-weight buffers: dequant is fused into both GEMMs.
static const size_t OFF_COUNTS = 0;
static const size_t OFF_LISTS  = 256;
static const size_t OFF_WLISTS = OFF_LISTS + (size_t)T_TOKENS * E_NUM * 4;       // 65792
static const size_t OFF_XB     = 131328;
static const size_t OFF_ACT    = OFF_XB + (size_t)T_TOKENS * H_DIM * 2;           // xb 8 MB
static const size_t OFF_TMP    = OFF_ACT + (size_t)2 * T_TOKENS * I_DIM * 2;      // act 11.5 MB
// tmp 33.5 MB; total ~53 MB

// async global->LDS, 16 B per lane; LDS dest is wave-uniform base + lane*16.
__device__ __forceinline__ void gload_lds16(const bf16* g, bf16* l)
{
    __builtin_amdgcn_global_load_lds((const __attribute__((address_space(1))) void*)g,
                                     (__attribute__((address_space(3))) void*)l,
                                     16, 0, 0);
}

// ================= K1: prep = xconv (2048) + router (8) =================
__global__ __launch_bounds__(256) void prep_kernel(
    const float* __restrict__ x,
    bf16*        __restrict__ xb,
    const float* __restrict__ logits,
    int*         __restrict__ counts,
    int*         __restrict__ lists,
    float*       __restrict__ wlists)
{
    const int bid = blockIdx.x;
    const int tid = threadIdx.x;

    if (bid < 2048) {
        // ---- xconv: f32 -> bf16, 8 elems/thread ----
        const int i = bid * 256 + tid;
        const float4* x4 = reinterpret_cast<const float4*>(x) + (size_t)i * 2;
        float4 v0 = x4[0], v1 = x4[1];
        bf16x8 bv;
        bv[0] = (bf16)v0.x; bv[1] = (bf16)v0.y; bv[2] = (bf16)v0.z; bv[3] = (bf16)v0.w;
        bv[4] = (bf16)v1.x; bv[5] = (bf16)v1.y; bv[6] = (bf16)v1.z; bv[7] = (bf16)v1.w;
        *reinterpret_cast<bf16x8*>(xb + (size_t)i * 8) = bv;
    } else {
        // ---- router ----
        const int t = (bid - 2048) * 256 + tid;
        const float* l = logits + (size_t)t * E_NUM;
        float v0 = -1e30f, v1 = -1e30f;
        int i0 = 0, i1 = 0;
        #pragma unroll
        for (int e = 0; e < E_NUM; ++e) {
            float v = l[e];
            if (v > v0) { v1 = v0; i1 = i0; v0 = v; i0 = e; }
            else if (v > v1) { v1 = v; i1 = e; }
        }
        float w0 = 1.f / (1.f + __expf(v1 - v0));
        float w1 = 1.f - w0;
        int p0 = atomicAdd(&counts[i0], 1);
        lists[i0 * T_TOKENS + p0] = t * 2 + 0;
        wlists[i0 * T_TOKENS + p0] = w0;
        int p1 = atomicAdd(&counts[i1], 1);
        lists[i1 * T_TOKENS + p1] = t * 2 + 1;
        wlists[i1 * T_TOKENS + p1] = w1;
    }
}

// ================= GEMM1 M=64, fused dequant: xb @ dequant(W_gate_up)^T, SwiGLU =================
// R7 skeleton (M=64, ~6 blocks/CU TLP, 2-barrier loop) + R3's verified B-dequant
// staging: per k-tile each thread loads 8 q-ints x 4 granule-slots from gu_q,
// dequants in-reg, ds_writes to the SAME swizzled Bl layout the fragment reads
// expect (slot s holds row s>>3, logical granule (s&7)^(row&7)).
__global__ __launch_bounds__(256) void gemm1_kernel(
    const bf16*  __restrict__ xb,
    const int*   __restrict__ q,
    const float* __restrict__ sc,
    const int*   __restrict__ counts,
    const int*   __restrict__ lists,
    bf16*        __restrict__ act)
{
    // XCD-pinned: lid = (bid&7)*704 + bid>>3 -> expert = XCD; m-tile fastest.
    const int lid = (blockIdx.x & 7) * 704 + (blockIdx.x >> 3);
    const int e   = lid / 704;
    const int r_  = lid - e * 704;
    const int nt  = r_ >> 5;         // 0..21, 64 I-cols per tile
    const int m0  = (r_ & 31) << 6;  // 0..1984
    const int cnt = counts[e];
    if (m0 >= cnt) return;

    __shared__ __align__(16) bf16 Al[4096];    // 64 x 64
    __shared__ __align__(16) bf16 Bl[8192];    // 128 x 64
    __shared__ int meta[64];

    const int tid = threadIdx.x;
    if (tid < 64) {
        int m = m0 + tid;
        meta[tid] = lists[e * T_TOKENS + (m < cnt ? m : 0)];
    }
    __syncthreads();

    const int lane = tid & 63;
    const int wv = tid >> 6;
    const int wm = wv >> 1, wn = wv & 1;

    // A staging: 2 granule-slots/thread via global_load_lds (source pre-swizzle)
    size_t agbl[2];
    #pragma unroll
    for (int j = 0; j < 2; ++j) {
        int g = tid + 256 * j;
        int arow = g >> 3, cg = g & 7;
        agbl[j] = (size_t)(meta[arow] >> 1) * H_DIM + ((cg ^ (arow & 7)) * 8);
    }

    // B staging: 4 granule-slots/thread (slot s = tid + 256j, row = tid>>3 + 32j).
    // gl = (s&7)^(row&7) is j-invariant.
    const int gl = (tid & 7) ^ ((tid >> 3) & 7);
    const int*   qb_[4];
    const float* sb_[4];
    #pragma unroll
    for (int j = 0; j < 4; ++j) {
        int r     = (tid >> 3) + 32 * j;        // B-tile row 0..127
        int p2    = r >> 4;
        int is_up = p2 & 1;
        int icol  = nt * 64 + (p2 >> 1) * 16 + (r & 15);
        size_t row_q = (size_t)e * 2816 + (is_up ? I_DIM : 0) + icol;
        qb_[j] = q  + row_q * H_DIM + gl * 8;
        sb_[j] = sc + row_q * 16;
    }

    int afr[2][2], bfr[2][4];
    #pragma unroll
    for (int ks = 0; ks < 2; ++ks) {
        int gidx = ks * 4 + (lane >> 4);
        #pragma unroll
        for (int t4 = 0; t4 < 2; ++t4) {
            int ra = wm * 32 + t4 * 16 + (lane & 15);
            afr[ks][t4] = ra * 64 + ((gidx ^ (ra & 7)) * 8);
        }
        #pragma unroll
        for (int t4 = 0; t4 < 4; ++t4) {
            int rb = wn * 64 + t4 * 16 + (lane & 15);
            bfr[ks][t4] = rb * 64 + ((gidx ^ (rb & 7)) * 8);
        }
    }

    floatx4 acc[2][4];
    #pragma unroll
    for (int i = 0; i < 2; ++i)
        #pragma unroll
        for (int j = 0; j < 4; ++j)
            acc[i][j] = (floatx4){0.f, 0.f, 0.f, 0.f};

    for (int kt = 0; kt < 32; ++kt) {
        const int k0 = kt * 64;
        #pragma unroll
        for (int j = 0; j < 2; ++j)
            gload_lds16(xb + agbl[j] + k0, &Al[(tid + 256 * j) * 8]);
        #pragma unroll
        for (int j = 0; j < 4; ++j) {
            const int4* p = reinterpret_cast<const int4*>(qb_[j] + k0);
            int4 a = p[0], c = p[1];
            float s = sb_[j][kt >> 1];
            float m8 = -8.f * s;
            bf16x8 bv;
            bv[0] = (bf16)fmaf((float)a.x, s, m8);
            bv[1] = (bf16)fmaf((float)a.y, s, m8);
            bv[2] = (bf16)fmaf((float)a.z, s, m8);
            bv[3] = (bf16)fmaf((float)a.w, s, m8);
            bv[4] = (bf16)fmaf((float)c.x, s, m8);
            bv[5] = (bf16)fmaf((float)c.y, s, m8);
            bv[6] = (bf16)fmaf((float)c.z, s, m8);
            bv[7] = (bf16)fmaf((float)c.w, s, m8);
            *reinterpret_cast<bf16x8*>(&Bl[(tid + 256 * j) * 8]) = bv;
        }
        __syncthreads();
        #pragma unroll
        for (int ks = 0; ks < 2; ++ks) {
            bf16x8 af[2], bff[4];
            #pragma unroll
            for (int mt = 0; mt < 2; ++mt)
                af[mt] = *reinterpret_cast<const bf16x8*>(&Al[afr[ks][mt]]);
            #pragma unroll
            for (int ntf = 0; ntf < 4; ++ntf)
                bff[ntf] = *reinterpret_cast<const bf16x8*>(&Bl[bfr[ks][ntf]]);
            #pragma unroll
            for (int mt = 0; mt < 2; ++mt)
                #pragma unroll
                for (int ntf = 0; ntf < 4; ++ntf)
                    acc[mt][ntf] = __builtin_amdgcn_mfma_f32_16x16x32_bf16(af[mt], bff[ntf], acc[mt][ntf], 0, 0, 0);
        }
        __syncthreads();
    }

    // epilogue: SwiGLU (gate = even col-frag, up = odd), scatter to act
    const int rbase = (lane >> 4) * 4;
    const int cn = lane & 15;
    #pragma unroll
    for (int mt = 0; mt < 2; ++mt) {
        #pragma unroll
        for (int j = 0; j < 2; ++j) {
            floatx4 g = acc[mt][2 * j];
            floatx4 u = acc[mt][2 * j + 1];
            int col = nt * 64 + (wn * 2 + j) * 16 + cn;
            #pragma unroll
            for (int r = 0; r < 4; ++r) {
                int lrow = wm * 32 + mt * 16 + rbase + r;
                if (m0 + lrow < cnt) {
                    float gate = g[r], up = u[r];
                    float a = gate / (1.f + __expf(-gate)) * up;
                    act[(size_t)meta[lrow] * I_DIM + col] = (bf16)a;
                }
            }
        }
    }
}

// ================= GEMM2 M=64, fused dequant: act @ dequant(W_down)^T -> tmp =================
__global__ __launch_bounds__(256) void gemm2_kernel(
    const bf16*  __restrict__ act,
    const int*   __restrict__ q,
    const float* __restrict__ sc,
    const int*   __restrict__ counts,
    const int*   __restrict__ lists,
    const float* __restrict__ wlists,
    float*       __restrict__ tmp)
{
    // 4096 = 8 * 512, one expert per XCD, m-tile fastest
    const int lid = (blockIdx.x & 7) * 512 + (blockIdx.x >> 3);
    const int e   = lid >> 9;
    const int r_  = lid & 511;
    const int nt  = r_ >> 5;        // 0..15, 128 H-cols per tile
    const int m0  = (r_ & 31) << 6;
    const int cnt = counts[e];
    if (m0 >= cnt) return;

    __shared__ __align__(16) bf16 Al[4096];
    __shared__ __align__(16) bf16 Bl[8192];
    __shared__ int   meta[64];
    __shared__ float wmeta[64];

    const int tid = threadIdx.x;
    if (tid < 64) {
        int m = m0 + tid;
        int mm = (m < cnt) ? m : 0;
        meta[tid]  = lists[e * T_TOKENS + mm];
        wmeta[tid] = wlists[e * T_TOKENS + mm];
    }
    __syncthreads();

    const int lane = tid & 63;
    const int wv = tid >> 6;
    const int wm = wv >> 1, wn = wv & 1;

    size_t agbl[2];
    #pragma unroll
    for (int j = 0; j < 2; ++j) {
        int g = tid + 256 * j;
        int arow = g >> 3, cg = g & 7;
        agbl[j] = (size_t)meta[arow] * I_DIM + ((cg ^ (arow & 7)) * 8);
    }

    const int gl = (tid & 7) ^ ((tid >> 3) & 7);
    const int*   qb_[4];
    const float* sb_[4];
    #pragma unroll
    for (int j = 0; j < 4; ++j) {
        int r = (tid >> 3) + 32 * j;            // B-tile row 0..127 (H row nt*128+r)
        size_t row_q = (size_t)e * 2048 + nt * 128 + r;
        qb_[j] = q  + row_q * I_DIM + gl * 8;
        sb_[j] = sc + row_q * 11;
    }

    int afr[2][2], bfr[2][4];
    #pragma unroll
    for (int ks = 0; ks < 2; ++ks) {
        int gidx = ks * 4 + (lane >> 4);
        #pragma unroll
        for (int t4 = 0; t4 < 2; ++t4) {
            int ra = wm * 32 + t4 * 16 + (lane & 15);
            afr[ks][t4] = ra * 64 + ((gidx ^ (ra & 7)) * 8);
        }
        #pragma unroll
        for (int t4 = 0; t4 < 4; ++t4) {
            int rb = wn * 64 + t4 * 16 + (lane & 15);
            bfr[ks][t4] = rb * 64 + ((gidx ^ (rb & 7)) * 8);
        }
    }

    floatx4 acc[2][4];
    #pragma unroll
    for (int i = 0; i < 2; ++i)
        #pragma unroll
        for (int j = 0; j < 4; ++j)
            acc[i][j] = (floatx4){0.f, 0.f, 0.f, 0.f};

    for (int kt = 0; kt < 22; ++kt) {
        const int k0 = kt * 64;
        #pragma unroll
        for (int j = 0; j < 2; ++j)
            gload_lds16(act + agbl[j] + k0, &Al[(tid + 256 * j) * 8]);
        #pragma unroll
        for (int j = 0; j < 4; ++j) {
            const int4* p = reinterpret_cast<const int4*>(qb_[j] + k0);
            int4 a = p[0], c = p[1];
            float s = sb_[j][kt >> 1];
            float m8 = -8.f * s;
            bf16x8 bv;
            bv[0] = (bf16)fmaf((float)a.x, s, m8);
            bv[1] = (bf16)fmaf((float)a.y, s, m8);
            bv[2] = (bf16)fmaf((float)a.z, s, m8);
            bv[3] = (bf16)fmaf((float)a.w, s, m8);
            bv[4] = (bf16)fmaf((float)c.x, s, m8);
            bv[5] = (bf16)fmaf((float)c.y, s, m8);
            bv[6] = (bf16)fmaf((float)c.z, s, m8);
            bv[7] = (bf16)fmaf((float)c.w, s, m8);
            *reinterpret_cast<bf16x8*>(&Bl[(tid + 256 * j) * 8]) = bv;
        }
        __syncthreads();
        #pragma unroll
        for (int ks = 0; ks < 2; ++ks) {
            bf16x8 af[2], bff[4];
            #pragma unroll
            for (int mt = 0; mt < 2; ++mt)
                af[mt] = *reinterpret_cast<const bf16x8*>(&Al[afr[ks][mt]]);
            #pragma unroll
            for (int ntf = 0; ntf < 4; ++ntf)
                bff[ntf] = *reinterpret_cast<const bf16x8*>(&Bl[bfr[ks][ntf]]);
            #pragma unroll
            for (int mt = 0; mt < 2; ++mt)
                #pragma unroll
                for (int ntf = 0; ntf < 4; ++ntf)
                    acc[mt][ntf] = __builtin_amdgcn_mfma_f32_16x16x32_bf16(af[mt], bff[ntf], acc[mt][ntf], 0, 0, 0);
        }
        __syncthreads();
    }

    const int rbase = (lane >> 4) * 4;
    const int cn = lane & 15;
    #pragma unroll
    for (int mt = 0; mt < 2; ++mt) {
        #pragma unroll
        for (int ntf = 0; ntf < 4; ++ntf) {
            floatx4 v = acc[mt][ntf];
            int col = nt * 128 + wn * 64 + ntf * 16 + cn;
            #pragma unroll
            for (int r = 0; r < 4; ++r) {
                int lrow = wm * 32 + mt * 16 + rbase + r;
                if (m0 + lrow < cnt) {
                    tmp[(size_t)meta[lrow] * H_DIM + col] = wmeta[lrow] * v[r];
                }
            }
        }
    }
}

// ---------------- finalize: out[t] = tmp[2t] + tmp[2t+1] ----------------
__global__ void finalize_kernel(const float* __restrict__ tmp, float* __restrict__ out)
{
    int i4 = blockIdx.x * blockDim.x + threadIdx.x;
    int t  = i4 >> 9;
    int h  = (i4 & 511) * 4;
    float4 a = *reinterpret_cast<const float4*>(tmp + ((size_t)2 * t) * H_DIM + h);
    float4 b = *reinterpret_cast<const float4*>(tmp + ((size_t)(2 * t + 1)) * H_DIM + h);
    float4 o;
    o.x = a.x + b.x; o.y = a.y + b.y; o.z = a.z + b.z; o.w = a.w + b.w;
    *reinterpret_cast<float4*>(out + (size_t)t * H_DIM + h) = o;
}

extern "C" void kernel_launch(void* const* d_in, const int* in_sizes, int n_in,
                              void* d_out, int out_size, void* d_ws, size_t ws_size,
                              hipStream_t stream)
{
    const float* router_logits = (const float*)d_in[0];
    const float* x             = (const float*)d_in[1];
    const int*   gu_q          = (const int*)d_in[2];
    const float* gu_s          = (const float*)d_in[3];
    const int*   dn_q          = (const int*)d_in[4];
    const float* dn_s          = (const float*)d_in[5];
    float* out = (float*)d_out;

    char* ws = (char*)d_ws;
    int*   counts = (int*)(ws + OFF_COUNTS);
    int*   lists  = (int*)(ws + OFF_LISTS);
    float* wlists = (float*)(ws + OFF_WLISTS);
    bf16*  xb     = (bf16*)(ws + OFF_XB);
    bf16*  act    = (bf16*)(ws + OFF_ACT);
    float* tmp    = (float*)(ws + OFF_TMP);

    hipMemsetAsync(counts, 0, E_NUM * sizeof(int), stream);

    prep_kernel<<<2056, 256, 0, stream>>>(x, xb, router_logits, counts, lists, wlists);
    gemm1_kernel<<<5632, 256, 0, stream>>>(xb, gu_q, gu_s, counts, lists, act);
    gemm2_kernel<<<4096, 256, 0, stream>>>(act, dn_q, dn_s, counts, lists, wlists, tmp);
    finalize_kernel<<<4096, 256, 0, stream>>>(tmp, out);
}

// Round 13
// 487.881 us; speedup vs baseline: 1.1205x; 1.1205x over previous
//
#include <hip/hip_runtime.h>
#include <hip/hip_bf16.h>

#define T_TOKENS 2048
#define H_DIM    2048
#define I_DIM    1408
#define E_NUM    8

typedef __bf16 bf16;
typedef __attribute__((ext_vector_type(8))) __bf16  bf16x8;
typedef __attribute__((ext_vector_type(4))) float   floatx4;

// ---------------- ws layout (bytes) ----------------
// gu_pk: [E][22 n-tiles][32 k-tiles][128 r][8 g] bf16x8, XOR-swizzled granules = 92.3 MB
// dn_pk: [E][16 n-tiles][22 k-tiles][128 r][8 g] bf16x8, swizzled              = 46.1 MB
// tmp (4096 slots x 2048 f32 = 33.5 MB) overlaps gu_pk (dead after gemm1).
static const size_t OFF_COUNTS = 0;
static const size_t OFF_LISTS  = 256;
static const size_t OFF_WLISTS = OFF_LISTS + (size_t)T_TOKENS * E_NUM * 4;       // 65792
static const size_t OFF_XB     = 131328;                                          // 8 MB
static const size_t OFF_ACT    = OFF_XB + (size_t)T_TOKENS * H_DIM * 2;           // 11.5 MB
static const size_t OFF_GUPK   = OFF_ACT + (size_t)2 * T_TOKENS * I_DIM * 2;
static const size_t OFF_DNPK   = OFF_GUPK + (size_t)E_NUM * 22 * 32 * 16384;
static const size_t OFF_TMP    = OFF_GUPK;   // 33.5 MB, overlapped with gu_pk

// async global->LDS, 16 B per lane; LDS dest is wave-uniform base + lane*16.
__device__ __forceinline__ void gload_lds16(const bf16* g, bf16* l)
{
    __builtin_amdgcn_global_load_lds((const __attribute__((address_space(1))) void*)g,
                                     (__attribute__((address_space(3))) void*)l,
                                     16, 0, 0);
}

// ================= K1: prep = pack_gu (5632) + xconv (2048) + router (8) =================
__global__ __launch_bounds__(256) void prep_kernel(
    const int*   __restrict__ gu_q,
    const float* __restrict__ gu_s,
    bf16*        __restrict__ gu_pk,
    const float* __restrict__ x,
    bf16*        __restrict__ xb,
    const float* __restrict__ logits,
    int*         __restrict__ counts,
    int*         __restrict__ lists,
    float*       __restrict__ wlists)
{
    const int bid = blockIdx.x;
    const int tid = threadIdx.x;

    if (bid < 5632) {
        // ---- pack_gu v2: one block per output tile, linear 16 KB writes ----
        const int kt  = bid & 31;
        const int en  = bid >> 5;
        const int nt  = en % 22;
        const int e   = en / 22;
        bf16x8* ob = reinterpret_cast<bf16x8*>(gu_pk) + (size_t)bid * 1024;
        #pragma unroll
        for (int j = 0; j < 4; ++j) {
            const int s     = tid + 256 * j;
            const int r     = s >> 3;
            const int gl    = (s & 7) ^ (r & 7);
            const int p2    = r >> 4;
            const int is_up = p2 & 1;
            const int icol  = nt * 64 + (p2 >> 1) * 16 + (r & 15);
            const size_t row_q = (size_t)e * 2816 + (is_up ? I_DIM : 0) + icol;
            const int4* qp = reinterpret_cast<const int4*>(gu_q + row_q * H_DIM + kt * 64 + gl * 8);
            int4 a = qp[0], c = qp[1];
            float sv = gu_s[row_q * 16 + (kt >> 1)];
            float m8 = -8.f * sv;
            bf16x8 bv;
            bv[0] = (bf16)fmaf((float)a.x, sv, m8);
            bv[1] = (bf16)fmaf((float)a.y, sv, m8);
            bv[2] = (bf16)fmaf((float)a.z, sv, m8);
            bv[3] = (bf16)fmaf((float)a.w, sv, m8);
            bv[4] = (bf16)fmaf((float)c.x, sv, m8);
            bv[5] = (bf16)fmaf((float)c.y, sv, m8);
            bv[6] = (bf16)fmaf((float)c.z, sv, m8);
            bv[7] = (bf16)fmaf((float)c.w, sv, m8);
            ob[s] = bv;
        }
    } else if (bid < 5632 + 2048) {
        // ---- xconv: f32 -> bf16, 8 elems/thread ----
        const int i = (bid - 5632) * 256 + tid;
        const float4* x4 = reinterpret_cast<const float4*>(x) + (size_t)i * 2;
        float4 v0 = x4[0], v1 = x4[1];
        bf16x8 bv;
        bv[0] = (bf16)v0.x; bv[1] = (bf16)v0.y; bv[2] = (bf16)v0.z; bv[3] = (bf16)v0.w;
        bv[4] = (bf16)v1.x; bv[5] = (bf16)v1.y; bv[6] = (bf16)v1.z; bv[7] = (bf16)v1.w;
        *reinterpret_cast<bf16x8*>(xb + (size_t)i * 8) = bv;
    } else {
        // ---- router ----
        const int t = (bid - 7680) * 256 + tid;
        const float* l = logits + (size_t)t * E_NUM;
        float v0 = -1e30f, v1 = -1e30f;
        int i0 = 0, i1 = 0;
        #pragma unroll
        for (int e = 0; e < E_NUM; ++e) {
            float v = l[e];
            if (v > v0) { v1 = v0; i1 = i0; v0 = v; i0 = e; }
            else if (v > v1) { v1 = v; i1 = e; }
        }
        float w0 = 1.f / (1.f + __expf(v1 - v0));
        float w1 = 1.f - w0;
        int p0 = atomicAdd(&counts[i0], 1);
        lists[i0 * T_TOKENS + p0] = t * 2 + 0;
        wlists[i0 * T_TOKENS + p0] = w0;
        int p1 = atomicAdd(&counts[i1], 1);
        lists[i1 * T_TOKENS + p1] = t * 2 + 1;
        wlists[i1 * T_TOKENS + p1] = w1;
    }
}

// ================= K2: gemm1 M=64 (blocks 0..5631) + pack_dn (5632..8447) =================
// M=64: ~1400 live gemm1 blocks (~5.5/CU) for inter-block TLP (the proven lever);
// LDS 24.6 KB/block. pack_dn co-resides, filling gemm1's idle bandwidth.
__global__ __launch_bounds__(256) void gemm1_packdn_kernel(
    const bf16*  __restrict__ xb,
    const bf16*  __restrict__ wpk,
    const int*   __restrict__ counts,
    const int*   __restrict__ lists,
    bf16*        __restrict__ act,
    const int*   __restrict__ dn_q,
    const float* __restrict__ dn_s,
    bf16*        __restrict__ dn_pk)
{
    const int tid = threadIdx.x;

    if (blockIdx.x >= 5632) {
        // ---- pack_dn v2: linear writes ----
        const int pbid = blockIdx.x - 5632;
        const int kt  = pbid % 22;
        const int en  = pbid / 22;
        const int nt  = en & 15;
        const int e   = en >> 4;
        bf16x8* ob = reinterpret_cast<bf16x8*>(dn_pk) + (size_t)pbid * 1024;
        #pragma unroll
        for (int j = 0; j < 4; ++j) {
            const int s  = tid + 256 * j;
            const int r  = s >> 3;
            const int gl = (s & 7) ^ (r & 7);
            const size_t row_q = (size_t)e * 2048 + nt * 128 + r;
            const int4* qp = reinterpret_cast<const int4*>(dn_q + row_q * I_DIM + kt * 64 + gl * 8);
            int4 a = qp[0], c = qp[1];
            float sv = dn_s[row_q * 11 + (kt >> 1)];
            float m8 = -8.f * sv;
            bf16x8 bv;
            bv[0] = (bf16)fmaf((float)a.x, sv, m8);
            bv[1] = (bf16)fmaf((float)a.y, sv, m8);
            bv[2] = (bf16)fmaf((float)a.z, sv, m8);
            bv[3] = (bf16)fmaf((float)a.w, sv, m8);
            bv[4] = (bf16)fmaf((float)c.x, sv, m8);
            bv[5] = (bf16)fmaf((float)c.y, sv, m8);
            bv[6] = (bf16)fmaf((float)c.z, sv, m8);
            bv[7] = (bf16)fmaf((float)c.w, sv, m8);
            ob[s] = bv;
        }
        return;
    }

    // ---- gemm1, M=64: xb @ W_gate_up^T, fused SwiGLU ----
    // XCD-pinned: lid = (bid&7)*704 + bid>>3 -> expert = XCD; m-tile fastest.
    const int lid = (blockIdx.x & 7) * 704 + (blockIdx.x >> 3);
    const int e   = lid / 704;
    const int r_  = lid - e * 704;
    const int nt  = r_ >> 5;         // 0..21, 64 I-cols per tile
    const int m0  = (r_ & 31) << 6;  // 0..1984
    const int cnt = counts[e];
    if (m0 >= cnt) return;

    __shared__ __align__(16) bf16 Al[4096];    // 64 x 64
    __shared__ __align__(16) bf16 Bl[8192];    // 128 x 64
    __shared__ int meta[64];

    if (tid < 64) {
        int m = m0 + tid;
        meta[tid] = lists[e * T_TOKENS + (m < cnt ? m : 0)];
    }
    __syncthreads();

    const int lane = tid & 63;
    const int wv = tid >> 6;
    const int wm = wv >> 1, wn = wv & 1;

    // A staging: 2 granule-slots/thread (slot g = tid + 256j, row = g>>3)
    size_t agbl[2];
    #pragma unroll
    for (int j = 0; j < 2; ++j) {
        int g = tid + 256 * j;
        int arow = g >> 3, cg = g & 7;
        agbl[j] = (size_t)(meta[arow] >> 1) * H_DIM + ((cg ^ (arow & 7)) * 8);
    }
    const bf16* bt = wpk + ((size_t)e * 22 + nt) * (32 * 8192) + tid * 8;

    // fragment read offsets: A rows wm*32 + mt*16, B rows wn*64 + t4*16
    int afr[2][2], bfr[2][4];
    #pragma unroll
    for (int ks = 0; ks < 2; ++ks) {
        int gidx = ks * 4 + (lane >> 4);
        #pragma unroll
        for (int t4 = 0; t4 < 2; ++t4) {
            int ra = wm * 32 + t4 * 16 + (lane & 15);
            afr[ks][t4] = ra * 64 + ((gidx ^ (ra & 7)) * 8);
        }
        #pragma unroll
        for (int t4 = 0; t4 < 4; ++t4) {
            int rb = wn * 64 + t4 * 16 + (lane & 15);
            bfr[ks][t4] = rb * 64 + ((gidx ^ (rb & 7)) * 8);
        }
    }

    floatx4 acc[2][4];
    #pragma unroll
    for (int i = 0; i < 2; ++i)
        #pragma unroll
        for (int j = 0; j < 4; ++j)
            acc[i][j] = (floatx4){0.f, 0.f, 0.f, 0.f};

    for (int k0 = 0; k0 < H_DIM; k0 += 64) {
        #pragma unroll
        for (int j = 0; j < 2; ++j)
            gload_lds16(xb + agbl[j] + k0, &Al[(tid + 256 * j) * 8]);
        const bf16* bsrc = bt + (size_t)(k0 >> 6) * 8192;
        #pragma unroll
        for (int j = 0; j < 4; ++j)
            gload_lds16(bsrc + j * 2048, &Bl[tid * 8 + j * 2048]);
        __syncthreads();
        #pragma unroll
        for (int ks = 0; ks < 2; ++ks) {
            bf16x8 af[2], bff[4];
            #pragma unroll
            for (int mt = 0; mt < 2; ++mt)
                af[mt] = *reinterpret_cast<const bf16x8*>(&Al[afr[ks][mt]]);
            #pragma unroll
            for (int ntf = 0; ntf < 4; ++ntf)
                bff[ntf] = *reinterpret_cast<const bf16x8*>(&Bl[bfr[ks][ntf]]);
            #pragma unroll
            for (int mt = 0; mt < 2; ++mt)
                #pragma unroll
                for (int ntf = 0; ntf < 4; ++ntf)
                    acc[mt][ntf] = __builtin_amdgcn_mfma_f32_16x16x32_bf16(af[mt], bff[ntf], acc[mt][ntf], 0, 0, 0);
        }
        __syncthreads();
    }

    // epilogue: SwiGLU (gate = even col-frag, up = odd), scatter to act
    const int rbase = (lane >> 4) * 4;
    const int cn = lane & 15;
    #pragma unroll
    for (int mt = 0; mt < 2; ++mt) {
        #pragma unroll
        for (int j = 0; j < 2; ++j) {
            floatx4 g = acc[mt][2 * j];
            floatx4 u = acc[mt][2 * j + 1];
            int col = nt * 64 + (wn * 2 + j) * 16 + cn;
            #pragma unroll
            for (int r = 0; r < 4; ++r) {
                int lrow = wm * 32 + mt * 16 + rbase + r;
                if (m0 + lrow < cnt) {
                    float gate = g[r], up = u[r];
                    float a = gate / (1.f + __expf(-gate)) * up;
                    act[(size_t)meta[lrow] * I_DIM + col] = (bf16)a;
                }
            }
        }
    }
}

// ---------------- GEMM2 M=64: act @ W_down^T, weighted write to tmp ----------------
__global__ __launch_bounds__(256) void gemm2_kernel(
    const bf16*  __restrict__ act,
    const bf16*  __restrict__ wpk,
    const int*   __restrict__ counts,
    const int*   __restrict__ lists,
    const float* __restrict__ wlists,
    float*       __restrict__ tmp)
{
    // 4096 = 8 * 512, one expert per XCD, m-tile fastest
    const int lid = (blockIdx.x & 7) * 512 + (blockIdx.x >> 3);
    const int e   = lid >> 9;
    const int r_  = lid & 511;
    const int nt  = r_ >> 5;        // 0..15, 128 H-cols per tile
    const int m0  = (r_ & 31) << 6;
    const int cnt = counts[e];
    if (m0 >= cnt) return;

    __shared__ __align__(16) bf16 Al[4096];
    __shared__ __align__(16) bf16 Bl[8192];
    __shared__ int   meta[64];
    __shared__ float wmeta[64];

    const int tid = threadIdx.x;
    if (tid < 64) {
        int m = m0 + tid;
        int mm = (m < cnt) ? m : 0;
        meta[tid]  = lists[e * T_TOKENS + mm];
        wmeta[tid] = wlists[e * T_TOKENS + mm];
    }
    __syncthreads();

    const int lane = tid & 63;
    const int wv = tid >> 6;
    const int wm = wv >> 1, wn = wv & 1;

    size_t agbl[2];
    #pragma unroll
    for (int j = 0; j < 2; ++j) {
        int g = tid + 256 * j;
        int arow = g >> 3, cg = g & 7;
        agbl[j] = (size_t)meta[arow] * I_DIM + ((cg ^ (arow & 7)) * 8);
    }
    const bf16* bt = wpk + ((size_t)e * 16 + nt) * (22 * 8192) + tid * 8;

    int afr[2][2], bfr[2][4];
    #pragma unroll
    for (int ks = 0; ks < 2; ++ks) {
        int gidx = ks * 4 + (lane >> 4);
        #pragma unroll
        for (int t4 = 0; t4 < 2; ++t4) {
            int ra = wm * 32 + t4 * 16 + (lane & 15);
            afr[ks][t4] = ra * 64 + ((gidx ^ (ra & 7)) * 8);
        }
        #pragma unroll
        for (int t4 = 0; t4 < 4; ++t4) {
            int rb = wn * 64 + t4 * 16 + (lane & 15);
            bfr[ks][t4] = rb * 64 + ((gidx ^ (rb & 7)) * 8);
        }
    }

    floatx4 acc[2][4];
    #pragma unroll
    for (int i = 0; i < 2; ++i)
        #pragma unroll
        for (int j = 0; j < 4; ++j)
            acc[i][j] = (floatx4){0.f, 0.f, 0.f, 0.f};

    for (int kt = 0; kt < 22; ++kt) {
        #pragma unroll
        for (int j = 0; j < 2; ++j)
            gload_lds16(act + agbl[j] + kt * 64, &Al[(tid + 256 * j) * 8]);
        const bf16* bsrc = bt + (size_t)kt * 8192;
        #pragma unroll
        for (int j = 0; j < 4; ++j)
            gload_lds16(bsrc + j * 2048, &Bl[tid * 8 + j * 2048]);
        __syncthreads();
        #pragma unroll
        for (int ks = 0; ks < 2; ++ks) {
            bf16x8 af[2], bff[4];
            #pragma unroll
            for (int mt = 0; mt < 2; ++mt)
                af[mt] = *reinterpret_cast<const bf16x8*>(&Al[afr[ks][mt]]);
            #pragma unroll
            for (int ntf = 0; ntf < 4; ++ntf)
                bff[ntf] = *reinterpret_cast<const bf16x8*>(&Bl[bfr[ks][ntf]]);
            #pragma unroll
            for (int mt = 0; mt < 2; ++mt)
                #pragma unroll
                for (int ntf = 0; ntf < 4; ++ntf)
                    acc[mt][ntf] = __builtin_amdgcn_mfma_f32_16x16x32_bf16(af[mt], bff[ntf], acc[mt][ntf], 0, 0, 0);
        }
        __syncthreads();
    }

    const int rbase = (lane >> 4) * 4;
    const int cn = lane & 15;
    #pragma unroll
    for (int mt = 0; mt < 2; ++mt) {
        #pragma unroll
        for (int ntf = 0; ntf < 4; ++ntf) {
            floatx4 v = acc[mt][ntf];
            int col = nt * 128 + wn * 64 + ntf * 16 + cn;
            #pragma unroll
            for (int r = 0; r < 4; ++r) {
                int lrow = wm * 32 + mt * 16 + rbase + r;
                if (m0 + lrow < cnt) {
                    tmp[(size_t)meta[lrow] * H_DIM + col] = wmeta[lrow] * v[r];
                }
            }
        }
    }
}

// ---------------- finalize: out[t] = tmp[2t] + tmp[2t+1] ----------------
__global__ void finalize_kernel(const float* __restrict__ tmp, float* __restrict__ out)
{
    int i4 = blockIdx.x * blockDim.x + threadIdx.x;
    int t  = i4 >> 9;
    int h  = (i4 & 511) * 4;
    float4 a = *reinterpret_cast<const float4*>(tmp + ((size_t)2 * t) * H_DIM + h);
    float4 b = *reinterpret_cast<const float4*>(tmp + ((size_t)(2 * t + 1)) * H_DIM + h);
    float4 o;
    o.x = a.x + b.x; o.y = a.y + b.y; o.z = a.z + b.z; o.w = a.w + b.w;
    *reinterpret_cast<float4*>(out + (size_t)t * H_DIM + h) = o;
}

extern "C" void kernel_launch(void* const* d_in, const int* in_sizes, int n_in,
                              void* d_out, int out_size, void* d_ws, size_t ws_size,
                              hipStream_t stream)
{
    const float* router_logits = (const float*)d_in[0];
    const float* x             = (const float*)d_in[1];
    const int*   gu_q          = (const int*)d_in[2];
    const float* gu_s          = (const float*)d_in[3];
    const int*   dn_q          = (const int*)d_in[4];
    const float* dn_s          = (const float*)d_in[5];
    float* out = (float*)d_out;

    char* ws = (char*)d_ws;
    int*   counts = (int*)(ws + OFF_COUNTS);
    int*   lists  = (int*)(ws + OFF_LISTS);
    float* wlists = (float*)(ws + OFF_WLISTS);
    bf16*  xb     = (bf16*)(ws + OFF_XB);
    bf16*  act    = (bf16*)(ws + OFF_ACT);
    bf16*  gu_pk  = (bf16*)(ws + OFF_GUPK);
    bf16*  dn_pk  = (bf16*)(ws + OFF_DNPK);
    float* tmp    = (float*)(ws + OFF_TMP);   // overlaps gu_pk (dead after gemm1)

    hipMemsetAsync(counts, 0, E_NUM * sizeof(int), stream);

    prep_kernel<<<7688, 256, 0, stream>>>(gu_q, gu_s, gu_pk, x, xb,
                                          router_logits, counts, lists, wlists);
    gemm1_packdn_kernel<<<8448, 256, 0, stream>>>(xb, gu_pk, counts, lists, act,
                                                  dn_q, dn_s, dn_pk);
    gemm2_kernel<<<4096, 256, 0, stream>>>(act, dn_pk, counts, lists, wlists, tmp);
    finalize_kernel<<<4096, 256, 0, stream>>>(tmp, out);
}